// Round 1
// baseline (67.051 us; speedup 1.0000x reference)
//
#include <hip/hip_runtime.h>
#include <hip/hip_bf16.h>

typedef __attribute__((ext_vector_type(8))) __bf16 bf16x8;
typedef __attribute__((ext_vector_type(4))) float f32x4;

#define SEQ   4096
#define HDIM  64
#define BKT   64
#define WIN   128

__device__ __forceinline__ unsigned short f2bf(float f) {
    unsigned int u = __float_as_uint(f);
    u += 0x7FFFu + ((u >> 16) & 1u);
    return (unsigned short)(u >> 16);
}

__global__ void __launch_bounds__(256) local_attn_kernel(
    const float* __restrict__ q, const float* __restrict__ k,
    const float* __restrict__ v, float* __restrict__ out)
{
    __shared__ __align__(16) unsigned short sQ[64 * 64];     // Q tile   [64 q][64 e]
    __shared__ __align__(16) unsigned short sKP[128 * 64];   // K window [128 k][64 e], reused as P [64 q][128 k]
    __shared__ __align__(16) unsigned short sVt[64 * 128];   // V^T      [64 e][128 k]

    const int tid = threadIdx.x;
    const int bid = blockIdx.x;
    const int bh = bid >> 6;
    const int bucket = bid & 63;

    const int qoff = (bh * SEQ + bucket * BKT) * HDIM;
    const int koff = qoff - BKT * HDIM;   // window start = bucket-1 (invalid rows handled below)

    const float scale = 0.125f;           // 64^-0.5, folded into Q staging

    // ---- stage Q (scaled), bf16, swizzled ----
    #pragma unroll
    for (int i = 0; i < 4; ++i) {
        int flat = i * 1024 + tid * 4;
        int row = flat >> 6, col = flat & 63;
        const float4 f = *reinterpret_cast<const float4*>(q + qoff + flat);
        uint2 pk;
        pk.x = (unsigned)f2bf(f.x * scale) | ((unsigned)f2bf(f.y * scale) << 16);
        pk.y = (unsigned)f2bf(f.z * scale) | ((unsigned)f2bf(f.w * scale) << 16);
        int byte = (row * 128 + col * 2) ^ ((row & 7) << 4);
        *reinterpret_cast<uint2*>(reinterpret_cast<char*>(sQ) + byte) = pk;
    }

    // ---- stage K window [128][64], zeros for bucket 0's backward pad ----
    #pragma unroll
    for (int i = 0; i < 8; ++i) {
        int flat = i * 1024 + tid * 4;
        int row = flat >> 6, col = flat & 63;
        float4 f = make_float4(0.f, 0.f, 0.f, 0.f);
        if (bucket > 0 || row >= BKT)
            f = *reinterpret_cast<const float4*>(k + koff + flat);
        uint2 pk;
        pk.x = (unsigned)f2bf(f.x) | ((unsigned)f2bf(f.y) << 16);
        pk.y = (unsigned)f2bf(f.z) | ((unsigned)f2bf(f.w) << 16);
        int byte = (row * 128 + col * 2) ^ ((row & 7) << 4);
        *reinterpret_cast<uint2*>(reinterpret_cast<char*>(sKP) + byte) = pk;
    }

    // ---- stage V transposed -> sVt[e][k], scalar writes, j-staggered ----
    #pragma unroll
    for (int i = 0; i < 8; ++i) {
        int flat = i * 1024 + tid * 4;
        int krow = flat >> 6, e0 = flat & 63;
        float4 f = make_float4(0.f, 0.f, 0.f, 0.f);
        if (bucket > 0 || krow >= BKT)
            f = *reinterpret_cast<const float4*>(v + koff + flat);
        float fv[4] = {f.x, f.y, f.z, f.w};
        #pragma unroll
        for (int jj = 0; jj < 4; ++jj) {
            int j = (jj + (tid & 15)) & 3;
            int er = e0 + j;
            int byte = (er * 256 + krow * 2) ^ ((er & 7) << 4);
            *reinterpret_cast<unsigned short*>(reinterpret_cast<char*>(sVt) + byte) = f2bf(fv[j]);
        }
    }
    __syncthreads();

    const int lane = tid & 63;
    const int wid = tid >> 6;
    const int g = lane >> 4, m = lane & 15;
    const int qbase = wid * 16;           // this wave's 16-query slab

    // ---- S = Q K^T : per wave 8 col-tiles x (K=64 -> 2 mfma) ----
    bf16x8 aq[2];
    #pragma unroll
    for (int h = 0; h < 2; ++h) {
        int row = qbase + m;
        int byte = (row * 128 + (h * 32 + g * 8) * 2) ^ ((row & 7) << 4);
        aq[h] = *reinterpret_cast<const bf16x8*>(reinterpret_cast<const char*>(sQ) + byte);
    }
    f32x4 acc[8];
    #pragma unroll
    for (int c = 0; c < 8; ++c) acc[c] = (f32x4){0.f, 0.f, 0.f, 0.f};
    #pragma unroll
    for (int c = 0; c < 8; ++c) {
        int row = c * 16 + m;
        #pragma unroll
        for (int h = 0; h < 2; ++h) {
            int byte = (row * 128 + (h * 32 + g * 8) * 2) ^ ((row & 7) << 4);
            bf16x8 bk = *reinterpret_cast<const bf16x8*>(reinterpret_cast<const char*>(sKP) + byte);
            acc[c] = __builtin_amdgcn_mfma_f32_16x16x32_bf16(aq[h], bk, acc[c], 0, 0, 0);
        }
    }
    __syncthreads();   // all waves done reading K; sKP becomes P

    // ---- mask + exact softmax. lane holds S[qbase+g*4+r][c*16+m] ----
    float rsum[4];
    #pragma unroll
    for (int r = 0; r < 4; ++r) {
        int q_i = qbase + g * 4 + r;      // query index within bucket
        float mxr = -1e30f;
        #pragma unroll
        for (int c = 0; c < 8; ++c) {
            int kj = c * 16 + m;          // key index within 128-window
            bool dead = (c >= 4) ? (kj - 64 > q_i) : (bucket == 0);
            float s = dead ? -1e30f : acc[c][r];
            acc[c][r] = s;
            mxr = fmaxf(mxr, s);
        }
        #pragma unroll
        for (int x = 1; x < 16; x <<= 1) mxr = fmaxf(mxr, __shfl_xor(mxr, x));
        float sr = 0.f;
        #pragma unroll
        for (int c = 0; c < 8; ++c) {
            float p = __expf(acc[c][r] - mxr);
            acc[c][r] = p;
            sr += p;
        }
        #pragma unroll
        for (int x = 1; x < 16; x <<= 1) sr += __shfl_xor(sr, x);
        rsum[r] = sr;
    }

    // ---- write P (unnormalized, bf16) into sKP as [64 q][128 k], swizzled ----
    #pragma unroll
    for (int c = 0; c < 8; ++c) {
        #pragma unroll
        for (int r = 0; r < 4; ++r) {
            int qr = qbase + g * 4 + r;
            int kj = c * 16 + m;
            int byte = (qr * 256 + kj * 2) ^ ((qr & 7) << 4);
            *reinterpret_cast<unsigned short*>(reinterpret_cast<char*>(sKP) + byte) = f2bf(acc[c][r]);
        }
    }
    __syncthreads();

    // ---- O = P V : A from P rows, B from V^T rows ----
    bf16x8 ap[4];
    #pragma unroll
    for (int kt = 0; kt < 4; ++kt) {
        int row = qbase + m;
        int byte = (row * 256 + (kt * 32 + g * 8) * 2) ^ ((row & 7) << 4);
        ap[kt] = *reinterpret_cast<const bf16x8*>(reinterpret_cast<const char*>(sKP) + byte);
    }
    f32x4 oacc[4];
    #pragma unroll
    for (int jt = 0; jt < 4; ++jt) oacc[jt] = (f32x4){0.f, 0.f, 0.f, 0.f};
    #pragma unroll
    for (int jt = 0; jt < 4; ++jt) {
        #pragma unroll
        for (int kt = 0; kt < 4; ++kt) {
            int row = jt * 16 + m;
            int byte = (row * 256 + (kt * 32 + g * 8) * 2) ^ ((row & 7) << 4);
            bf16x8 bv = *reinterpret_cast<const bf16x8*>(reinterpret_cast<const char*>(sVt) + byte);
            oacc[jt] = __builtin_amdgcn_mfma_f32_16x16x32_bf16(ap[kt], bv, oacc[jt], 0, 0, 0);
        }
    }

    // ---- epilogue: normalize and store fp32 ----
    #pragma unroll
    for (int r = 0; r < 4; ++r) {
        float rl = 1.0f / rsum[r];
        int orow = qoff + (qbase + g * 4 + r) * HDIM;
        #pragma unroll
        for (int jt = 0; jt < 4; ++jt) {
            out[orow + jt * 16 + m] = oacc[jt][r] * rl;
        }
    }
}

extern "C" void kernel_launch(void* const* d_in, const int* in_sizes, int n_in,
                              void* d_out, int out_size, void* d_ws, size_t ws_size,
                              hipStream_t stream) {
    const float* q = (const float*)d_in[0];
    const float* k = (const float*)d_in[1];
    const float* v = (const float*)d_in[2];
    float* out = (float*)d_out;
    const int bh = in_sizes[0] / (SEQ * HDIM);          // merged batch*heads = 64
    const int nblocks = bh * (SEQ / BKT);               // one block per (bh, bucket)
    hipLaunchKernelGGL(local_attn_kernel, dim3(nblocks), dim3(256), 0, stream,
                       q, k, v, out);
}

// Round 3
// 61.002 us; speedup vs baseline: 1.0992x; 1.0992x over previous
//
#include <hip/hip_runtime.h>
#include <hip/hip_bf16.h>

typedef __attribute__((ext_vector_type(8))) __bf16 bf16x8;
typedef __attribute__((ext_vector_type(4))) float f32x4;

#define SEQ   4096
#define HDIM  64
#define BKT   64

__device__ __forceinline__ unsigned f2bf_u(float f) {
    unsigned u = __float_as_uint(f);
    u += 0x7FFFu + ((u >> 16) & 1u);
    return u >> 16;
}
__device__ __forceinline__ unsigned pk2(float a, float b) {
    return f2bf_u(a) | (f2bf_u(b) << 16);
}

__global__ void __launch_bounds__(256, 8) local_attn_kernel(
    const float* __restrict__ q, const float* __restrict__ k,
    const float* __restrict__ v, float* __restrict__ out)
{
    __shared__ __align__(16) unsigned short sA[128 * 64];   // K [128 k][64 e] -> reused as P [64 q][128 k]
    __shared__ __align__(16) unsigned short sVt[64 * 128];  // V^T [64 e][128 k]

    const int tid = threadIdx.x;
    const int bid0 = blockIdx.x;
    // XCD-aware bijective swizzle: consecutive logical buckets share an XCD's L2
    const int lg = (bid0 & 7) * 512 + (bid0 >> 3);
    const int bh = lg >> 6;
    const int bucket = lg & 63;

    const int qoff = (bh * SEQ + bucket * BKT) * HDIM;
    const int koff = qoff - BKT * HDIM;

    const int lane = tid & 63;
    const int wid  = tid >> 6;
    const int g = lane >> 4, m = lane & 15;
    const int qbase = wid * 16;

    char* const sAb = reinterpret_cast<char*>(sA);
    char* const sVb = reinterpret_cast<char*>(sVt);

    // ---- Q fragments direct from global (scaled), no LDS ----
    const float scale = 0.125f;
    bf16x8 bq[2];
    #pragma unroll
    for (int h = 0; h < 2; ++h) {
        const float* qp = q + qoff + (qbase + m) * HDIM + h * 32 + g * 8;
        const float4 f0 = *reinterpret_cast<const float4*>(qp);
        const float4 f1 = *reinterpret_cast<const float4*>(qp + 4);
        uint4 u;
        u.x = pk2(f0.x * scale, f0.y * scale);
        u.y = pk2(f0.z * scale, f0.w * scale);
        u.z = pk2(f1.x * scale, f1.y * scale);
        u.w = pk2(f1.z * scale, f1.w * scale);
        bq[h] = __builtin_bit_cast(bf16x8, u);
    }

    // ---- stage K -> sA [128][64] bf16, swizzled, vector writes ----
    #pragma unroll
    for (int i = 0; i < 8; ++i) {
        const int flat = i * 1024 + tid * 4;
        const int row = flat >> 6, col = flat & 63;
        float4 f = make_float4(0.f, 0.f, 0.f, 0.f);
        if (bucket > 0 || i >= 4)
            f = *reinterpret_cast<const float4*>(k + koff + flat);
        uint2 p;
        p.x = pk2(f.x, f.y);
        p.y = pk2(f.z, f.w);
        const int byte = (row * 128 + col * 2) ^ ((row & 7) << 4);
        *reinterpret_cast<uint2*>(sAb + byte) = p;
    }

    // ---- stage V^T via in-register 4x4 shuffle transpose, vector writes ----
    #pragma unroll
    for (int i = 0; i < 8; ++i) {
        const int kb = i * 16 + wid * 4;      // this wave's 4 k-rows
        const int e0 = m * 4;
        float4 f = make_float4(0.f, 0.f, 0.f, 0.f);
        if (bucket > 0 || i >= 4)
            f = *reinterpret_cast<const float4*>(v + koff + (kb + g) * HDIM + e0);
        const unsigned P0 = pk2(f.x, f.y);    // (e0,e0+1) @ k=kb+g
        const unsigned P1 = pk2(f.z, f.w);    // (e0+2,e0+3) @ k=kb+g
        const unsigned own  = (g < 2) ? P0 : P1;
        const unsigned send = (g < 2) ? P1 : P0;
        const unsigned R = __shfl_xor(send, 32);
        const unsigned T = __shfl_xor(own, 16);
        const unsigned U = __shfl_xor(R, 16);
        const unsigned A0 = (g < 2) ? own : R;
        const unsigned A1 = (g < 2) ? T : U;
        const unsigned A2 = (g < 2) ? R : own;
        const unsigned A3 = (g < 2) ? U : T;
        const int s = g & 1;
        const unsigned k0 = s ? A1 : A0, k1 = s ? A0 : A1;
        const unsigned k2 = s ? A3 : A2, k3 = s ? A2 : A3;
        const unsigned G0 = s ? ((k0 >> 16) | (k1 & 0xFFFF0000u)) : ((k0 & 0xFFFFu) | (k1 << 16));
        const unsigned G1 = s ? ((k2 >> 16) | (k3 & 0xFFFF0000u)) : ((k2 & 0xFFFFu) | (k3 << 16));
        const int er = e0 + g;
        const int byte = (er * 256 + kb * 2) ^ ((er & 7) << 4);
        uint2 p; p.x = G0; p.y = G1;
        *reinterpret_cast<uint2*>(sVb + byte) = p;
    }
    __syncthreads();

    // ---- S^T = K · Q^T : lane holds S^T[c*16+g*4+r][qbase+m] ----
    f32x4 acc[8];
    #pragma unroll
    for (int c = 0; c < 8; ++c) acc[c] = (f32x4){0.f, 0.f, 0.f, 0.f};
    #pragma unroll
    for (int c = 0; c < 8; ++c) {
        const int krow = c * 16 + m;
        #pragma unroll
        for (int h = 0; h < 2; ++h) {
            const int byte = (krow * 128 + h * 64 + g * 16) ^ ((m & 7) << 4);
            const bf16x8 ak = *reinterpret_cast<const bf16x8*>(sAb + byte);
            acc[c] = __builtin_amdgcn_mfma_f32_16x16x32_bf16(ak, bq[h], acc[c], 0, 0, 0);
        }
    }

    // ---- mask + exact softmax (lane-local over k; butterfly over g) ----
    const int qb = qbase + m;           // query index within bucket
    const int g4 = g * 4;
    float mx = -3e38f;
    #pragma unroll
    for (int c = 0; c < 8; ++c) {
        #pragma unroll
        for (int r = 0; r < 4; ++r) {
            const int kk = c * 16 + g4 + r;          // key index within 128-window
            const bool dead = (c >= 4) ? (kk - 64 > qb) : (bucket == 0);
            const float s = dead ? -1e30f : acc[c][r];
            acc[c][r] = s;
            mx = fmaxf(mx, s);
        }
    }
    mx = fmaxf(mx, __shfl_xor(mx, 16));
    mx = fmaxf(mx, __shfl_xor(mx, 32));
    float sum = 0.f;
    uint2 pb[8];
    #pragma unroll
    for (int c = 0; c < 8; ++c) {
        const float p0 = __expf(acc[c][0] - mx);
        const float p1 = __expf(acc[c][1] - mx);
        const float p2 = __expf(acc[c][2] - mx);
        const float p3 = __expf(acc[c][3] - mx);
        sum += (p0 + p1) + (p2 + p3);
        pb[c].x = pk2(p0, p1);
        pb[c].y = pk2(p2, p3);
    }
    sum += __shfl_xor(sum, 16);
    sum += __shfl_xor(sum, 32);
    const float rl = 1.0f / sum;

    __syncthreads();   // all K reads done; sA becomes P

    // ---- write P rows (wave-local round trip, vector writes) ----
    const int qrow = qbase + m;
    #pragma unroll
    for (int c = 0; c < 8; ++c) {
        const int byte = (qrow * 256 + c * 32 + g * 8) ^ ((qrow & 7) << 4);
        *reinterpret_cast<uint2*>(sAb + byte) = pb[c];
    }

    // ---- O^T = V^T · P^T : A from sVt rows, B from own P rows ----
    bf16x8 bp[4];
    #pragma unroll
    for (int kt = 0; kt < 4; ++kt) {
        const int byte = (qrow * 256 + kt * 64 + g * 16) ^ ((qrow & 7) << 4);
        bp[kt] = *reinterpret_cast<const bf16x8*>(sAb + byte);
    }
    f32x4 oacc[4];
    #pragma unroll
    for (int et = 0; et < 4; ++et) oacc[et] = (f32x4){0.f, 0.f, 0.f, 0.f};
    #pragma unroll
    for (int et = 0; et < 4; ++et) {
        const int row = et * 16 + m;
        #pragma unroll
        for (int kt = 0; kt < 4; ++kt) {
            const int byte = (row * 256 + kt * 64 + g * 16) ^ ((row & 7) << 4);
            const bf16x8 av = *reinterpret_cast<const bf16x8*>(sVb + byte);
            oacc[et] = __builtin_amdgcn_mfma_f32_16x16x32_bf16(av, bp[kt], oacc[et], 0, 0, 0);
        }
    }

    // ---- epilogue: normalize, float4 stores (lane's col q = qrow) ----
    #pragma unroll
    for (int et = 0; et < 4; ++et) {
        f32x4 o = oacc[et];
        o[0] *= rl; o[1] *= rl; o[2] *= rl; o[3] *= rl;
        *reinterpret_cast<float4*>(out + qoff + qrow * HDIM + et * 16 + g4) =
            *reinterpret_cast<float4*>(&o);
    }
}

extern "C" void kernel_launch(void* const* d_in, const int* in_sizes, int n_in,
                              void* d_out, int out_size, void* d_ws, size_t ws_size,
                              hipStream_t stream) {
    const float* q = (const float*)d_in[0];
    const float* k = (const float*)d_in[1];
    const float* v = (const float*)d_in[2];
    float* out = (float*)d_out;
    const int bh = in_sizes[0] / (SEQ * HDIM);   // merged batch*heads = 64
    const int nblocks = bh * (SEQ / BKT);        // 4096
    hipLaunchKernelGGL(local_attn_kernel, dim3(nblocks), dim3(256), 0, stream,
                       q, k, v, out);
}

// Round 5
// 48.092 us; speedup vs baseline: 1.3942x; 1.2685x over previous
//
#include <hip/hip_runtime.h>
#include <hip/hip_bf16.h>

typedef __attribute__((ext_vector_type(8))) __bf16 bf16x8;
typedef __attribute__((ext_vector_type(4))) float f32x4;

#define SEQ   4096
#define HDIM  64
#define BKT   64

__device__ __forceinline__ unsigned f2bf_u(float f) {
    unsigned u = __float_as_uint(f);
    u += 0x7FFFu + ((u >> 16) & 1u);
    return u >> 16;
}
__device__ __forceinline__ unsigned pk2(float a, float b) {
    return f2bf_u(a) | (f2bf_u(b) << 16);
}

__global__ void __launch_bounds__(256, 4) local_attn_kernel(
    const float* __restrict__ q, const float* __restrict__ k,
    const float* __restrict__ v, float* __restrict__ out)
{
    __shared__ __align__(16) unsigned short sK[128 * 64];   // K window [128 k][64 e]
    __shared__ __align__(16) unsigned short sVt[64 * 128];  // V^T [64 e][128 k]

    const int tid = threadIdx.x;
    const int bid0 = blockIdx.x;
    // XCD-aware bijective swizzle (4096 = 8 * 512 exact)
    const int lg = (bid0 & 7) * 512 + (bid0 >> 3);
    const int bh = lg >> 6;
    const int bucket = lg & 63;

    const int qoff = (bh * SEQ + bucket * BKT) * HDIM;
    const int koff = qoff - BKT * HDIM;

    const int lane = tid & 63;
    const int wid  = tid >> 6;
    const int g = lane >> 4, m = lane & 15;
    const int qbase = wid * 16;

    char* const sKb = reinterpret_cast<char*>(sK);
    char* const sVb = reinterpret_cast<char*>(sVt);

    // ================= Phase A: issue ALL global loads into registers =================
    float4 kreg[8], vreg[8], qreg[4];
    #pragma unroll
    for (int i = 0; i < 8; ++i) {
        const int flat = i * 1024 + tid * 4;
        kreg[i] = make_float4(0.f, 0.f, 0.f, 0.f);
        if (bucket > 0 || i >= 4)
            kreg[i] = *reinterpret_cast<const float4*>(k + koff + flat);
    }
    #pragma unroll
    for (int i = 0; i < 8; ++i) {
        const int kb = i * 16 + wid * 4;
        vreg[i] = make_float4(0.f, 0.f, 0.f, 0.f);
        if (bucket > 0 || i >= 4)
            vreg[i] = *reinterpret_cast<const float4*>(v + koff + (kb + g) * HDIM + m * 4);
    }
    #pragma unroll
    for (int h = 0; h < 2; ++h) {
        const float* qp = q + qoff + (qbase + m) * HDIM + h * 32 + g * 8;
        qreg[2 * h]     = *reinterpret_cast<const float4*>(qp);
        qreg[2 * h + 1] = *reinterpret_cast<const float4*>(qp + 4);
    }

    // ================= Phase B: convert + LDS writes (vmcnt drains overlap) ==========
    // K -> sK [128][64] bf16, swizzled
    #pragma unroll
    for (int i = 0; i < 8; ++i) {
        const int flat = i * 1024 + tid * 4;
        const int row = flat >> 6, col = flat & 63;
        uint2 p;
        p.x = pk2(kreg[i].x, kreg[i].y);
        p.y = pk2(kreg[i].z, kreg[i].w);
        const int byte = (row * 128 + col * 2) ^ ((row & 7) << 4);
        *reinterpret_cast<uint2*>(sKb + byte) = p;
    }
    // V^T via in-register 4x4 shuffle transpose
    #pragma unroll
    for (int i = 0; i < 8; ++i) {
        const int kb = i * 16 + wid * 4;
        const int e0 = m * 4;
        const float4 f = vreg[i];
        const unsigned P0 = pk2(f.x, f.y);
        const unsigned P1 = pk2(f.z, f.w);
        const unsigned own  = (g < 2) ? P0 : P1;
        const unsigned send = (g < 2) ? P1 : P0;
        const unsigned R = __shfl_xor(send, 32);
        const unsigned T = __shfl_xor(own, 16);
        const unsigned U = __shfl_xor(R, 16);
        const unsigned A0 = (g < 2) ? own : R;
        const unsigned A1 = (g < 2) ? T : U;
        const unsigned A2 = (g < 2) ? R : own;
        const unsigned A3 = (g < 2) ? U : T;
        const int s = g & 1;
        const unsigned k0 = s ? A1 : A0, k1 = s ? A0 : A1;
        const unsigned k2 = s ? A3 : A2, k3 = s ? A2 : A3;
        const unsigned G0 = s ? ((k0 >> 16) | (k1 & 0xFFFF0000u)) : ((k0 & 0xFFFFu) | (k1 << 16));
        const unsigned G1 = s ? ((k2 >> 16) | (k3 & 0xFFFF0000u)) : ((k2 & 0xFFFFu) | (k3 << 16));
        const int er = e0 + g;
        const int byte = (er * 256 + kb * 2) ^ ((er & 7) << 4);
        uint2 p; p.x = G0; p.y = G1;
        *reinterpret_cast<uint2*>(sVb + byte) = p;
    }
    // Q fragments (scale includes log2e for exp2-domain softmax)
    const float scale = 0.125f * 1.44269504f;
    bf16x8 bq[2];
    #pragma unroll
    for (int h = 0; h < 2; ++h) {
        uint4 u;
        u.x = pk2(qreg[2 * h].x * scale, qreg[2 * h].y * scale);
        u.y = pk2(qreg[2 * h].z * scale, qreg[2 * h].w * scale);
        u.z = pk2(qreg[2 * h + 1].x * scale, qreg[2 * h + 1].y * scale);
        u.w = pk2(qreg[2 * h + 1].z * scale, qreg[2 * h + 1].w * scale);
        bq[h] = __builtin_bit_cast(bf16x8, u);
    }
    __syncthreads();   // the only barrier

    // ================= S^T = K * Q^T : lane holds S^T[c*16+g*4+r][qbase+m] ==========
    f32x4 acc[8];
    #pragma unroll
    for (int c = 0; c < 8; ++c) acc[c] = (f32x4){0.f, 0.f, 0.f, 0.f};
    __builtin_amdgcn_s_setprio(1);
    #pragma unroll
    for (int c = 0; c < 8; ++c) {
        const int krow = c * 16 + m;
        #pragma unroll
        for (int h = 0; h < 2; ++h) {
            const int byte = (krow * 128 + h * 64 + g * 16) ^ ((m & 7) << 4);
            const bf16x8 ak = *reinterpret_cast<const bf16x8*>(sKb + byte);
            acc[c] = __builtin_amdgcn_mfma_f32_16x16x32_bf16(ak, bq[h], acc[c], 0, 0, 0);
        }
    }
    __builtin_amdgcn_s_setprio(0);

    // ================= mask + exact softmax (exp2 domain) ===========================
    const int qb = qbase + m;
    const int g4 = g * 4;
    float mx = -3e38f;
    #pragma unroll
    for (int c = 0; c < 8; ++c) {
        #pragma unroll
        for (int r = 0; r < 4; ++r) {
            const int kk = c * 16 + g4 + r;
            const bool dead = (c >= 4) ? (kk - 64 > qb) : (bucket == 0);
            const float s = dead ? -1e30f : acc[c][r];
            acc[c][r] = s;
            mx = fmaxf(mx, s);
        }
    }
    mx = fmaxf(mx, __shfl_xor(mx, 16));
    mx = fmaxf(mx, __shfl_xor(mx, 32));
    float sum = 0.f;
    uint2 pb[8];
    #pragma unroll
    for (int c = 0; c < 8; ++c) {
        const float p0 = __builtin_amdgcn_exp2f(acc[c][0] - mx);
        const float p1 = __builtin_amdgcn_exp2f(acc[c][1] - mx);
        const float p2 = __builtin_amdgcn_exp2f(acc[c][2] - mx);
        const float p3 = __builtin_amdgcn_exp2f(acc[c][3] - mx);
        sum += (p0 + p1) + (p2 + p3);
        pb[c].x = pk2(p0, p1);
        pb[c].y = pk2(p2, p3);
    }
    sum += __shfl_xor(sum, 16);
    sum += __shfl_xor(sum, 32);
    const float rl = 1.0f / sum;

    // ================= P redistribution via shuffles (no LDS, no barrier) ===========
    // dest lane (g,m), tile kt needs P[kt*32+g*8+j][qbase+m], j=0..7:
    //   first 4 from lane (2*(g&1), m), next 4 from lane (2*(g&1)+1, m),
    //   register c = 2*kt + (g>>1).
    const int l0 = m + ((g & 1) << 5);   // m + 16*(2*(g&1))
    const int l1 = l0 + 16;
    const bool hi = (g >> 1) != 0;
    bf16x8 bp[4];
    #pragma unroll
    for (int kt = 0; kt < 4; ++kt) {
        const unsigned a0x = __shfl(pb[2 * kt].x, l0),     a0y = __shfl(pb[2 * kt].y, l0);
        const unsigned a1x = __shfl(pb[2 * kt + 1].x, l0), a1y = __shfl(pb[2 * kt + 1].y, l0);
        const unsigned b0x = __shfl(pb[2 * kt].x, l1),     b0y = __shfl(pb[2 * kt].y, l1);
        const unsigned b1x = __shfl(pb[2 * kt + 1].x, l1), b1y = __shfl(pb[2 * kt + 1].y, l1);
        uint4 u;
        u.x = hi ? a1x : a0x;
        u.y = hi ? a1y : a0y;
        u.z = hi ? b1x : b0x;
        u.w = hi ? b1y : b0y;
        bp[kt] = __builtin_bit_cast(bf16x8, u);
    }

    // ================= O^T = V^T * P^T ==============================================
    f32x4 oacc[4];
    #pragma unroll
    for (int et = 0; et < 4; ++et) oacc[et] = (f32x4){0.f, 0.f, 0.f, 0.f};
    __builtin_amdgcn_s_setprio(1);
    #pragma unroll
    for (int et = 0; et < 4; ++et) {
        const int row = et * 16 + m;
        #pragma unroll
        for (int kt = 0; kt < 4; ++kt) {
            const int byte = (row * 256 + kt * 64 + g * 16) ^ ((row & 7) << 4);
            const bf16x8 av = *reinterpret_cast<const bf16x8*>(sVb + byte);
            oacc[et] = __builtin_amdgcn_mfma_f32_16x16x32_bf16(av, bp[kt], oacc[et], 0, 0, 0);
        }
    }
    __builtin_amdgcn_s_setprio(0);

    // ================= epilogue: normalize, float4 stores ===========================
    const int qrow = qbase + m;
    #pragma unroll
    for (int et = 0; et < 4; ++et) {
        f32x4 o = oacc[et];
        o[0] *= rl; o[1] *= rl; o[2] *= rl; o[3] *= rl;
        *reinterpret_cast<float4*>(out + qoff + qrow * HDIM + et * 16 + g4) =
            *reinterpret_cast<float4*>(&o);
    }
}

extern "C" void kernel_launch(void* const* d_in, const int* in_sizes, int n_in,
                              void* d_out, int out_size, void* d_ws, size_t ws_size,
                              hipStream_t stream) {
    const float* q = (const float*)d_in[0];
    const float* k = (const float*)d_in[1];
    const float* v = (const float*)d_in[2];
    float* out = (float*)d_out;
    const int bh = in_sizes[0] / (SEQ * HDIM);   // merged batch*heads = 64
    const int nblocks = bh * (SEQ / BKT);        // 4096
    hipLaunchKernelGGL(local_attn_kernel, dim3(nblocks), dim3(256), 0, stream,
                       q, k, v, out);
}